// Round 8
// baseline (1528.768 us; speedup 1.0000x reference)
//
#include <hip/hip_runtime.h>
#include <hip/hip_bf16.h>
#include <math.h>

#define BATCH 1024

typedef __attribute__((ext_vector_type(8))) short bf16x8;
typedef __attribute__((ext_vector_type(4))) float f32x4;

// Padded NHWC activation geometry: [34 rows][34 cols][64 ci] bf16, 147968 B/img
#define IMG_ELEMS 73984
#define PIX_B 128
#define ROW_B 4352            // 34 * 128
// LDS tile: 10 rows x 34 px, pixel stride 144 B (conflict-free ds_read_b128)
#define LPIX_B 144
#define LROW_B 4896           // 34 * 144

// ---------------- weight prep: 4x OIHW fp32 [64][64][3][3] -> bf16 [tap][co][ci] ----------------
__global__ __launch_bounds__(256) void prep_weights(
    const float* __restrict__ w0, const float* __restrict__ w1,
    const float* __restrict__ w2, const float* __restrict__ w3,
    __hip_bfloat16* __restrict__ dst)
{
    int tid = blockIdx.x * 256 + threadIdx.x;
    if (tid >= 4 * 36864) return;
    int c = tid / 36864, r = tid - c * 36864;
    int tap = r / 4096, r2 = r - tap * 4096;
    int co = r2 >> 6, ci = r2 & 63;
    const float* src = (c == 0) ? w0 : (c == 1) ? w1 : (c == 2) ? w2 : w3;
    float v = src[((size_t)co * 64 + ci) * 9 + tap];
    dst[tid] = __float2bfloat16(v);
}

// ---------------- zero pad borders of [cb][34][34][64] bf16 buffer ----------------
__global__ __launch_bounds__(256) void zero_borders(__hip_bfloat16* __restrict__ buf, int cb)
{
    int tid = blockIdx.x * 256 + threadIdx.x;
    int total = cb * 132 * 8;
    if (tid >= total) return;
    int img = tid / 1056, r = tid - img * 1056;
    int pxi = r >> 3, chunk = r & 7;
    int pix;
    if (pxi < 34)       pix = pxi;
    else if (pxi < 68)  pix = 33 * 34 + (pxi - 34);
    else if (pxi < 100) pix = (pxi - 68 + 1) * 34;
    else                pix = (pxi - 100 + 1) * 34 + 33;
    uint4 z = {0, 0, 0, 0};
    *(uint4*)((char*)buf + (size_t)img * 147968 + pix * PIX_B + chunk * 16) = z;
}

// ---------------- LeNet (conv1+conv2+FC+argmax+conf+flags), 1 block = 1 image ----------------
__global__ __launch_bounds__(256) void lenet_full(
    const float* __restrict__ x,
    const float* __restrict__ lw1, const float* __restrict__ lb1,
    const float* __restrict__ lw2, const float* __restrict__ lb2,
    const float* __restrict__ fw1, const float* __restrict__ fb1,
    const float* __restrict__ fw2, const float* __restrict__ fb2,
    const float* __restrict__ fw3, const float* __restrict__ fb3,
    const int* __restrict__ labels, const float* __restrict__ thr,
    float* __restrict__ out, float* __restrict__ conf, int* __restrict__ flags)
{
    __shared__ float xs[3072];
    __shared__ float wl1[450];
    __shared__ float bl1[6];
    __shared__ float wl2[2400];
    __shared__ float bl2[16];
    __shared__ float p1[1176];
    __shared__ float p2[400];
    __shared__ float ps[256];
    __shared__ float h1[120];
    __shared__ float h2[84];
    __shared__ float lg[10];

    int img = blockIdx.x, t = threadIdx.x;
    const float* xi = x + (size_t)img * 3072;
    for (int i = t; i < 3072; i += 256) xs[i] = xi[i];
    for (int i = t; i < 450; i += 256) wl1[i] = lw1[i];
    if (t < 6) bl1[t] = lb1[t];
    for (int i = t; i < 2400; i += 256) wl2[i] = lw2[i];
    if (t < 16) bl2[t] = lb2[t];
    __syncthreads();

    for (int idx = t; idx < 1176; idx += 256) {
        int o = idx / 196, r = idx - o * 196, py = r / 14, px = r - py * 14;
        int y0 = 2 * py, x0 = 2 * px;
        float s00, s01, s10, s11;
        s00 = s01 = s10 = s11 = bl1[o];
        for (int c = 0; c < 3; c++) {
            float pv[6][6];
            #pragma unroll
            for (int i2 = 0; i2 < 6; i2++)
                #pragma unroll
                for (int j2 = 0; j2 < 6; j2++)
                    pv[i2][j2] = xs[c * 1024 + (y0 + i2) * 32 + x0 + j2];
            const float* wc = &wl1[o * 75 + c * 25];
            #pragma unroll
            for (int ky = 0; ky < 5; ky++)
                #pragma unroll
                for (int kx = 0; kx < 5; kx++) {
                    float wv = wc[ky * 5 + kx];
                    s00 += pv[ky][kx] * wv;
                    s01 += pv[ky][kx + 1] * wv;
                    s10 += pv[ky + 1][kx] * wv;
                    s11 += pv[ky + 1][kx + 1] * wv;
                }
        }
        float mm = fmaxf(fmaxf(s00, s01), fmaxf(s10, s11));
        p1[idx] = fmaxf(mm, 0.f);
    }
    __syncthreads();

    for (int idx = t; idx < 400; idx += 256) {
        int o = idx / 25, r = idx - o * 25, py = r / 5, px = r - py * 5;
        int y0 = 2 * py, x0 = 2 * px;
        float s00, s01, s10, s11;
        s00 = s01 = s10 = s11 = bl2[o];
        for (int c = 0; c < 6; c++) {
            float pv[6][6];
            #pragma unroll
            for (int i2 = 0; i2 < 6; i2++)
                #pragma unroll
                for (int j2 = 0; j2 < 6; j2++)
                    pv[i2][j2] = p1[c * 196 + (y0 + i2) * 14 + x0 + j2];
            const float* wc = &wl2[o * 150 + c * 25];
            #pragma unroll
            for (int ky = 0; ky < 5; ky++)
                #pragma unroll
                for (int kx = 0; kx < 5; kx++) {
                    float wv = wc[ky * 5 + kx];
                    s00 += pv[ky][kx] * wv;
                    s01 += pv[ky][kx + 1] * wv;
                    s10 += pv[ky + 1][kx] * wv;
                    s11 += pv[ky + 1][kx + 1] * wv;
                }
        }
        float mm = fmaxf(fmaxf(s00, s01), fmaxf(s10, s11));
        p2[idx] = fmaxf(mm, 0.f);
    }
    __syncthreads();

    {
        int n = t & 127, half = t >> 7;
        float s = 0.f;
        if (n < 120) {
            int k0 = half * 200;
            for (int k = k0; k < k0 + 200; k++) s += p2[k] * fw1[k * 120 + n];
        }
        ps[t] = s;
    }
    __syncthreads();
    if (t < 120) h1[t] = fmaxf(ps[t] + ps[t + 128] + fb1[t], 0.f);
    __syncthreads();
    {
        int n = t & 127, half = t >> 7;
        float s = 0.f;
        if (n < 84) {
            int k0 = half * 60;
            for (int k = k0; k < k0 + 60; k++) s += h1[k] * fw2[k * 84 + n];
        }
        ps[t] = s;
    }
    __syncthreads();
    if (t < 84) h2[t] = fmaxf(ps[t] + ps[t + 128] + fb2[t], 0.f);
    __syncthreads();
    if (t < 10) {
        float s = fb3[t];
        for (int k = 0; k < 84; k++) s += h2[k] * fw3[k * 10 + t];
        lg[t] = s;
        out[(size_t)img * 10 + t] = s;
    }
    __syncthreads();
    if (t == 0) {
        int pred = 0;
        float mm = lg[0];
        #pragma unroll
        for (int j = 1; j < 10; j++) if (lg[j] > mm) { mm = lg[j]; pred = j; }
        float se = 0.f, m2 = -1e30f;
        #pragma unroll
        for (int j = 0; j < 10; j++) {
            se += expf(lg[j] - mm);
            if (j != pred) m2 = fmaxf(m2, lg[j]);
        }
        float gap = (1.f - expf(m2 - mm)) / se;
        flags[img] = (gap <= thr[0]) ? 1 : 0;
        atomicAdd(&conf[labels[img] * 10 + pred], 1.f);
    }
}

// ---------------- conv0: NCHW fp32 [3][32][32] -> padded NHWC bf16, bias+ReLU ----------------
__global__ __launch_bounds__(256) void conv0_nhwc(const float* __restrict__ x,
    const float* __restrict__ w, const float* __restrict__ bias,
    __hip_bfloat16* __restrict__ out, int cb)
{
    __shared__ float sl[3][10][34];
    __shared__ float wl[1728];
    __shared__ float bl[64];
    int bid = blockIdx.x;
    int img = bid % cb, strip = bid / cb;
    int r0 = strip * 8;
    int t = threadIdx.x;
    const float* xi = x + (size_t)img * 3072;
    for (int i = t; i < 1020; i += 256) {
        int c = i / 340, rr2 = i - c * 340;
        int rr = rr2 / 34, cc = rr2 - rr * 34;
        int y = r0 + rr - 1, xx = cc - 1;
        float v = 0.f;
        if (y >= 0 && y < 32 && xx >= 0 && xx < 32) v = xi[c * 1024 + y * 32 + xx];
        sl[c][rr][cc] = v;
    }
    for (int i = t; i < 1728; i += 256) wl[i] = w[i];
    if (t < 64) bl[t] = bias[t];
    __syncthreads();

    int rr = t >> 5, col = t & 31;
    float iv[27];
    #pragma unroll
    for (int c = 0; c < 3; c++)
        #pragma unroll
        for (int dy = 0; dy < 3; dy++)
            #pragma unroll
            for (int dx = 0; dx < 3; dx++)
                iv[c * 9 + dy * 3 + dx] = sl[c][rr + dy][col + dx];

    __hip_bfloat16 ov[64];
    #pragma unroll 4
    for (int co = 0; co < 64; co++) {
        float s = bl[co];
        const float* wc = &wl[co * 27];
        #pragma unroll
        for (int k = 0; k < 27; k++) s += iv[k] * wc[k];
        ov[co] = __float2bfloat16(fmaxf(s, 0.f));
    }
    int pix = (r0 + rr + 1) * 34 + (col + 1);
    uint4* dst = (uint4*)((char*)out + (size_t)img * 147968 + pix * PIX_B);
    const uint4* srcv = (const uint4*)ov;
    #pragma unroll
    for (int j = 0; j < 8; j++) dst[j] = srcv[j];
}

// ---------------- 3x3 SAME conv: persistent per-image block, pipelined strips ----------------
// grid = cb (1 block = 1 image), 256 thr / 4 waves. Loops 4 strips of 8 rows.
// While strip s's 18-step K-loop runs (16 MFMA/step, round-5 proven shape),
// strip s+1's 43.5 KB staging is already in flight into registers (11 x
// dwordx4 per thread) -> HBM latency hidden under compute, memory queue
// stays occupied. Single 49 KB LDS tile (2 blocks/CU at grid=cb), conflict-
// free 144 B pixel stride; depth-3 B reg-ring; LDS-bounce coalesced epilogue.
// MEAN: whole image in one block -> msum written directly, no atomics.
template<bool ADD, bool MEAN>
__global__ __launch_bounds__(256, 2) void conv3x3_pipe(
    const __hip_bfloat16* __restrict__ act, const __hip_bfloat16* __restrict__ wts,
    const float* __restrict__ bias, const __hip_bfloat16* __restrict__ skip,
    __hip_bfloat16* __restrict__ out, float* __restrict__ msum)
{
    __shared__ char sl[10 * LROW_B];   // 48960 B
    __shared__ float pmean[4][64];
    int img = blockIdx.x, t = threadIdx.x;
    int w = t >> 6, lane = t & 63;
    int m = lane & 15, q = lane >> 4;

    const char* gimg = (const char*)act + (size_t)img * 147968;
    char* oimg = (char*)out + (size_t)img * 147968;
    const char* simg = (const char*)skip + (size_t)img * 147968;

    // ---- staging: 2720 x 16B chunks per strip, 11 slots/thread ----
    uint4 pf[11];
    #define PREFETCH(s)                                                        \
        {                                                                      \
            const char* g_ = gimg + (size_t)((s) * 8) * ROW_B;                 \
            _Pragma("unroll")                                                  \
            for (int k = 0; k < 11; k++) {                                     \
                int u = t + 256 * k;                                           \
                if (u < 2720) pf[k] = *(const uint4*)(g_ + u * 16);            \
            }                                                                  \
        }
    #define STAGEWRITE()                                                       \
        {                                                                      \
            _Pragma("unroll")                                                  \
            for (int k = 0; k < 11; k++) {                                     \
                int u = t + 256 * k;                                           \
                if (u < 2720)                                                  \
                    *(uint4*)(sl + (u >> 3) * LPIX_B + (u & 7) * 16) = pf[k];  \
            }                                                                  \
        }

    // ---- fragment base offsets (identical every strip: buffer reused) ----
    int abase[4];
    #pragma unroll
    for (int mt = 0; mt < 4; mt++)
        abase[mt] = (2 * w + (mt >> 1)) * LROW_B + ((mt & 1) * 16 + m) * LPIX_B + q * 16;
    const char* wb = (const char*)wts;
    int bbase[4];
    #pragma unroll
    for (int nt = 0; nt < 4; nt++)
        bbase[nt] = (nt * 16 + m) * 128 + q * 16;

    #define ALOAD(s, buf)                                                      \
        {                                                                      \
            const int tap_ = (s) >> 1, kb_ = (s) & 1;                          \
            const int dy_ = tap_ / 3, dx_ = tap_ - dy_ * 3;                    \
            const int aoff_ = dy_ * LROW_B + dx_ * LPIX_B + kb_ * 64;          \
            _Pragma("unroll")                                                  \
            for (int mt = 0; mt < 4; mt++)                                     \
                a[buf][mt] = *(const bf16x8*)(sl + abase[mt] + aoff_);         \
        }
    #define BLOAD(s, buf)                                                      \
        {                                                                      \
            const int boff_ = ((s) >> 1) * 8192 + ((s) & 1) * 64;              \
            _Pragma("unroll")                                                  \
            for (int nt = 0; nt < 4; nt++)                                     \
                b[buf][nt] = *(const bf16x8*)(wb + bbase[nt] + boff_);         \
        }

    // ---- prologue: stage strip 0 ----
    PREFETCH(0)
    STAGEWRITE()
    __syncthreads();

    float s8[8];
    #pragma unroll
    for (int e = 0; e < 8; e++) s8[e] = 0.f;

    #pragma unroll
    for (int s = 0; s < 4; s++) {
        if (s < 3) PREFETCH(s + 1)          // in flight during the K-loop

        f32x4 acc[4][4] = {};
        bf16x8 a[2][4], b[3][4];
        BLOAD(0, 0) BLOAD(1, 1) BLOAD(2, 2)
        ALOAD(0, 0)
        #pragma unroll
        for (int ks = 0; ks < 18; ks++) {
            int cur = ks & 1;
            if (ks < 17) ALOAD(ks + 1, cur ^ 1)
            #pragma unroll
            for (int mt = 0; mt < 4; mt++)
                #pragma unroll
                for (int nt = 0; nt < 4; nt++)
                    acc[mt][nt] = __builtin_amdgcn_mfma_f32_16x16x32_bf16(
                        a[cur][mt], b[ks % 3][nt], acc[mt][nt], 0, 0, 0);
            if (ks + 3 < 18) BLOAD(ks + 3, (ks + 3) % 3)
        }

        __syncthreads();   // barA: all K-loop LDS reads done before bounce overwrite

        // bounce: acc+bias -> bf16 -> sl [px 0..255][co]
        #pragma unroll
        for (int nt = 0; nt < 4; nt++) {
            float bv = bias[nt * 16 + m];
            #pragma unroll
            for (int mt = 0; mt < 4; mt++) {
                int pl = (2 * w + (mt >> 1)) * 32 + (mt & 1) * 16 + q * 4;
                #pragma unroll
                for (int r = 0; r < 4; r++) {
                    __hip_bfloat16 hv = __float2bfloat16(acc[mt][nt][r] + bv);
                    *(__hip_bfloat16*)(sl + (size_t)(pl + r) * LPIX_B + (nt * 16 + m) * 2) = hv;
                }
            }
        }
        __syncthreads();   // barB: bounce visible cross-wave

        // coalesced global phase: 8 passes x 1KB-contiguous per wave
        int j = t & 7, pxl = t >> 3;
        #pragma unroll
        for (int pass = 0; pass < 8; pass++) {
            int goff = ((s * 8 + pass + 1) * 34 + (pxl + 1)) * PIX_B + j * 16;
            bf16x8 v = *(const bf16x8*)(sl + (size_t)(pxl + 32 * pass) * LPIX_B + j * 16);
            bf16x8 o;
            if (ADD) {
                bf16x8 sv = *(const bf16x8*)(simg + goff);
                #pragma unroll
                for (int e = 0; e < 8; e++) {
                    float f = __bfloat162float(((__hip_bfloat16*)&v)[e])
                            + __bfloat162float(((__hip_bfloat16*)&sv)[e]);
                    f = fmaxf(f, 0.f);
                    if (MEAN) s8[e] += f;
                    ((__hip_bfloat16*)&o)[e] = __float2bfloat16(f);
                }
            } else {
                #pragma unroll
                for (int e = 0; e < 8; e++) {
                    float f = fmaxf(__bfloat162float(((__hip_bfloat16*)&v)[e]), 0.f);
                    ((__hip_bfloat16*)&o)[e] = __float2bfloat16(f);
                }
            }
            *(bf16x8*)(oimg + goff) = o;
        }
        __syncthreads();   // barC: bounce reads done before restage

        if (s < 3) {
            STAGEWRITE()
            __syncthreads();   // barD: next strip staged
        }
    }
    #undef ALOAD
    #undef BLOAD
    #undef PREFETCH
    #undef STAGEWRITE

    if (MEAN) {
        #pragma unroll
        for (int off = 8; off <= 32; off <<= 1)
            #pragma unroll
            for (int e = 0; e < 8; e++) s8[e] += __shfl_xor(s8[e], off, 64);
        if (lane < 8)
            #pragma unroll
            for (int e = 0; e < 8; e++) pmean[w][(lane & 7) * 8 + e] = s8[e];
        __syncthreads();
        if (t < 64)
            msum[(size_t)img * 64 + t] =
                pmean[0][t] + pmean[1][t] + pmean[2][t] + pmean[3][t];
    }
}

// ---------------- final: mean-scale + FC + masked merge ----------------
__global__ __launch_bounds__(256) void res_fc(const float* __restrict__ msum,
    const float* __restrict__ rfc, const float* __restrict__ rfb,
    const int* __restrict__ flags, float* __restrict__ out)
{
    int idx = blockIdx.x * 256 + threadIdx.x;
    if (idx >= BATCH * 10) return;
    int img = idx / 10, d = idx - img * 10;
    if (!flags[img]) return;
    const float* mrow = msum + (size_t)img * 64;
    float s = rfb[d];
    for (int c = 0; c < 64; c++) s += mrow[c] * (1.f / 1024.f) * rfc[c * 10 + d];
    out[idx] = s;
}

extern "C" void kernel_launch(void* const* d_in, const int* in_sizes, int n_in,
                              void* d_out, int out_size, void* d_ws, size_t ws_size,
                              hipStream_t stream)
{
    const float* x    = (const float*)d_in[0];
    const float* thr  = (const float*)d_in[1];
    const int*   labels = (const int*)d_in[2];
    const float* lw1 = (const float*)d_in[3];  const float* lb1 = (const float*)d_in[4];
    const float* lw2 = (const float*)d_in[5];  const float* lb2 = (const float*)d_in[6];
    const float* lfc1 = (const float*)d_in[7]; const float* lfb1 = (const float*)d_in[8];
    const float* lfc2 = (const float*)d_in[9]; const float* lfb2 = (const float*)d_in[10];
    const float* lfc3 = (const float*)d_in[11];const float* lfb3 = (const float*)d_in[12];
    const float* rw0 = (const float*)d_in[13]; const float* rb0 = (const float*)d_in[14];
    const float* rw1a = (const float*)d_in[15];const float* rb1a = (const float*)d_in[16];
    const float* rw1b = (const float*)d_in[17];const float* rb1b = (const float*)d_in[18];
    const float* rw2a = (const float*)d_in[19];const float* rb2a = (const float*)d_in[20];
    const float* rw2b = (const float*)d_in[21];const float* rb2b = (const float*)d_in[22];
    const float* rfc = (const float*)d_in[23]; const float* rfb = (const float*)d_in[24];

    float* out  = (float*)d_out;
    float* conf = out + (size_t)BATCH * 10;

    int nc = 2;
    while (nc < 16 &&
           2ull * (size_t)(BATCH / nc) * 147968ull + 294912ull + 4096ull + 262144ull > ws_size)
        nc <<= 1;
    int cb = BATCH / nc;

    __hip_bfloat16* A  = (__hip_bfloat16*)d_ws;
    __hip_bfloat16* Bb = A + (size_t)cb * IMG_ELEMS;
    __hip_bfloat16* wprep = Bb + (size_t)cb * IMG_ELEMS;
    int* flags = (int*)((char*)wprep + 294912);
    float* msum = (float*)(flags + 1024);

    hipMemsetAsync(conf, 0, 100 * sizeof(float), stream);

    prep_weights<<<(4 * 36864 + 255) / 256, 256, 0, stream>>>(rw1a, rw1b, rw2a, rw2b, wprep);

    int zb = (cb * 1056 + 255) / 256;
    zero_borders<<<zb, 256, 0, stream>>>(A, cb);
    zero_borders<<<zb, 256, 0, stream>>>(Bb, cb);

    lenet_full<<<BATCH, 256, 0, stream>>>(x,
        lw1, lb1, lw2, lb2, lfc1, lfb1, lfc2, lfb2, lfc3, lfb3,
        labels, thr, out, conf, flags);

    const __hip_bfloat16* W1a = wprep;
    const __hip_bfloat16* W1b = wprep + 36864;
    const __hip_bfloat16* W2a = wprep + 2 * 36864;
    const __hip_bfloat16* W2b = wprep + 3 * 36864;

    for (int c0 = 0; c0 < BATCH; c0 += cb) {
        const float* xc = x + (size_t)c0 * 3072;
        conv0_nhwc<<<cb * 4, 256, 0, stream>>>(xc, rw0, rb0, A, cb);
        conv3x3_pipe<false, false><<<cb, 256, 0, stream>>>(A,  W1a, rb1a, nullptr, Bb, nullptr);
        conv3x3_pipe<true,  false><<<cb, 256, 0, stream>>>(Bb, W1b, rb1b, A, A, nullptr);
        conv3x3_pipe<false, false><<<cb, 256, 0, stream>>>(A,  W2a, rb2a, nullptr, Bb, nullptr);
        conv3x3_pipe<true,  true ><<<cb, 256, 0, stream>>>(Bb, W2b, rb2b, A, A,
                                                           msum + (size_t)c0 * 64);
    }

    res_fc<<<(BATCH * 10 + 255) / 256, 256, 0, stream>>>(msum, rfc, rfb, flags, out);
}

// Round 9
// 1178.437 us; speedup vs baseline: 1.2973x; 1.2973x over previous
//
#include <hip/hip_runtime.h>
#include <hip/hip_bf16.h>
#include <math.h>

#define BATCH 1024

typedef __attribute__((ext_vector_type(8))) short bf16x8;
typedef __attribute__((ext_vector_type(4))) float f32x4;

// Activation layout (TRANSPOSED-OCTET, padded NHWC'):
//   byte addr = img*147968 + row*4352 + c8*544 + col*16
// i.e. [34 rows][8 ci-octets][34 cols][16B granule of 8 bf16 ci].
// Row stride 4352 B; granule (row,c8,col) holds ci = c8*8..c8*8+7.
// This makes a strip's 10 rows a CONTIGUOUS 43520 B region (global_load_lds
// DMA-able) while keeping A-fragment ds_read_b128 bank-balanced (bank class
// = (2*c8 + col) mod 8 -> exactly 8 dwords/bank, the wave64 minimum).
#define IMG_ELEMS 73984
#define IMG_B 147968
#define ROW_B 4352
#define C8_B 544

__device__ __forceinline__ void async_g2l(const void* g, void* l)
{
    __builtin_amdgcn_global_load_lds(
        (const __attribute__((address_space(1))) void*)g,
        (__attribute__((address_space(3))) void*)l,
        16, 0, 0);
}

// ---------------- weight prep: 4x OIHW fp32 [64][64][3][3] -> bf16 [tap][co][ci] ----------------
__global__ __launch_bounds__(256) void prep_weights(
    const float* __restrict__ w0, const float* __restrict__ w1,
    const float* __restrict__ w2, const float* __restrict__ w3,
    __hip_bfloat16* __restrict__ dst)
{
    int tid = blockIdx.x * 256 + threadIdx.x;
    if (tid >= 4 * 36864) return;
    int c = tid / 36864, r = tid - c * 36864;
    int tap = r / 4096, r2 = r - tap * 4096;
    int co = r2 >> 6, ci = r2 & 63;
    const float* src = (c == 0) ? w0 : (c == 1) ? w1 : (c == 2) ? w2 : w3;
    float v = src[((size_t)co * 64 + ci) * 9 + tap];
    dst[tid] = __float2bfloat16(v);
}

// ---------------- zero pad borders (new layout) ----------------
__global__ __launch_bounds__(256) void zero_borders(__hip_bfloat16* __restrict__ buf, int cb)
{
    int tid = blockIdx.x * 256 + threadIdx.x;
    int total = cb * 132 * 8;
    if (tid >= total) return;
    int img = tid / 1056, r = tid - img * 1056;
    int pxi = r >> 3, c8 = r & 7;
    int row, col;
    if (pxi < 34)       { row = 0;              col = pxi; }
    else if (pxi < 68)  { row = 33;             col = pxi - 34; }
    else if (pxi < 100) { row = pxi - 68 + 1;   col = 0; }
    else                { row = pxi - 100 + 1;  col = 33; }
    uint4 z = {0, 0, 0, 0};
    *(uint4*)((char*)buf + (size_t)img * IMG_B + row * ROW_B + c8 * C8_B + col * 16) = z;
}

// ---------------- LeNet (conv1+conv2+FC+argmax+conf+flags), 1 block = 1 image ----------------
__global__ __launch_bounds__(256) void lenet_full(
    const float* __restrict__ x,
    const float* __restrict__ lw1, const float* __restrict__ lb1,
    const float* __restrict__ lw2, const float* __restrict__ lb2,
    const float* __restrict__ fw1, const float* __restrict__ fb1,
    const float* __restrict__ fw2, const float* __restrict__ fb2,
    const float* __restrict__ fw3, const float* __restrict__ fb3,
    const int* __restrict__ labels, const float* __restrict__ thr,
    float* __restrict__ out, float* __restrict__ conf, int* __restrict__ flags)
{
    __shared__ float xs[3072];
    __shared__ float wl1[450];
    __shared__ float bl1[6];
    __shared__ float wl2[2400];
    __shared__ float bl2[16];
    __shared__ float p1[1176];
    __shared__ float p2[400];
    __shared__ float ps[256];
    __shared__ float h1[120];
    __shared__ float h2[84];
    __shared__ float lg[10];

    int img = blockIdx.x, t = threadIdx.x;
    const float* xi = x + (size_t)img * 3072;
    for (int i = t; i < 3072; i += 256) xs[i] = xi[i];
    for (int i = t; i < 450; i += 256) wl1[i] = lw1[i];
    if (t < 6) bl1[t] = lb1[t];
    for (int i = t; i < 2400; i += 256) wl2[i] = lw2[i];
    if (t < 16) bl2[t] = lb2[t];
    __syncthreads();

    for (int idx = t; idx < 1176; idx += 256) {
        int o = idx / 196, r = idx - o * 196, py = r / 14, px = r - py * 14;
        int y0 = 2 * py, x0 = 2 * px;
        float s00, s01, s10, s11;
        s00 = s01 = s10 = s11 = bl1[o];
        for (int c = 0; c < 3; c++) {
            float pv[6][6];
            #pragma unroll
            for (int i2 = 0; i2 < 6; i2++)
                #pragma unroll
                for (int j2 = 0; j2 < 6; j2++)
                    pv[i2][j2] = xs[c * 1024 + (y0 + i2) * 32 + x0 + j2];
            const float* wc = &wl1[o * 75 + c * 25];
            #pragma unroll
            for (int ky = 0; ky < 5; ky++)
                #pragma unroll
                for (int kx = 0; kx < 5; kx++) {
                    float wv = wc[ky * 5 + kx];
                    s00 += pv[ky][kx] * wv;
                    s01 += pv[ky][kx + 1] * wv;
                    s10 += pv[ky + 1][kx] * wv;
                    s11 += pv[ky + 1][kx + 1] * wv;
                }
        }
        float mm = fmaxf(fmaxf(s00, s01), fmaxf(s10, s11));
        p1[idx] = fmaxf(mm, 0.f);
    }
    __syncthreads();

    for (int idx = t; idx < 400; idx += 256) {
        int o = idx / 25, r = idx - o * 25, py = r / 5, px = r - py * 5;
        int y0 = 2 * py, x0 = 2 * px;
        float s00, s01, s10, s11;
        s00 = s01 = s10 = s11 = bl2[o];
        for (int c = 0; c < 6; c++) {
            float pv[6][6];
            #pragma unroll
            for (int i2 = 0; i2 < 6; i2++)
                #pragma unroll
                for (int j2 = 0; j2 < 6; j2++)
                    pv[i2][j2] = p1[c * 196 + (y0 + i2) * 14 + x0 + j2];
            const float* wc = &wl2[o * 150 + c * 25];
            #pragma unroll
            for (int ky = 0; ky < 5; ky++)
                #pragma unroll
                for (int kx = 0; kx < 5; kx++) {
                    float wv = wc[ky * 5 + kx];
                    s00 += pv[ky][kx] * wv;
                    s01 += pv[ky][kx + 1] * wv;
                    s10 += pv[ky + 1][kx] * wv;
                    s11 += pv[ky + 1][kx + 1] * wv;
                }
        }
        float mm = fmaxf(fmaxf(s00, s01), fmaxf(s10, s11));
        p2[idx] = fmaxf(mm, 0.f);
    }
    __syncthreads();

    {
        int n = t & 127, half = t >> 7;
        float s = 0.f;
        if (n < 120) {
            int k0 = half * 200;
            for (int k = k0; k < k0 + 200; k++) s += p2[k] * fw1[k * 120 + n];
        }
        ps[t] = s;
    }
    __syncthreads();
    if (t < 120) h1[t] = fmaxf(ps[t] + ps[t + 128] + fb1[t], 0.f);
    __syncthreads();
    {
        int n = t & 127, half = t >> 7;
        float s = 0.f;
        if (n < 84) {
            int k0 = half * 60;
            for (int k = k0; k < k0 + 60; k++) s += h1[k] * fw2[k * 84 + n];
        }
        ps[t] = s;
    }
    __syncthreads();
    if (t < 84) h2[t] = fmaxf(ps[t] + ps[t + 128] + fb2[t], 0.f);
    __syncthreads();
    if (t < 10) {
        float s = fb3[t];
        for (int k = 0; k < 84; k++) s += h2[k] * fw3[k * 10 + t];
        lg[t] = s;
        out[(size_t)img * 10 + t] = s;
    }
    __syncthreads();
    if (t == 0) {
        int pred = 0;
        float mm = lg[0];
        #pragma unroll
        for (int j = 1; j < 10; j++) if (lg[j] > mm) { mm = lg[j]; pred = j; }
        float se = 0.f, m2 = -1e30f;
        #pragma unroll
        for (int j = 0; j < 10; j++) {
            se += expf(lg[j] - mm);
            if (j != pred) m2 = fmaxf(m2, lg[j]);
        }
        float gap = (1.f - expf(m2 - mm)) / se;
        flags[img] = (gap <= thr[0]) ? 1 : 0;
        atomicAdd(&conf[labels[img] * 10 + pred], 1.f);
    }
}

// ---------------- conv0: NCHW fp32 [3][32][32] -> transposed-octet bf16, bias+ReLU ----------------
__global__ __launch_bounds__(256) void conv0_nhwc(const float* __restrict__ x,
    const float* __restrict__ w, const float* __restrict__ bias,
    __hip_bfloat16* __restrict__ out, int cb)
{
    __shared__ float sl[3][10][34];
    __shared__ float wl[1728];
    __shared__ float bl[64];
    int bid = blockIdx.x;
    int img = bid % cb, strip = bid / cb;
    int r0 = strip * 8;
    int t = threadIdx.x;
    const float* xi = x + (size_t)img * 3072;
    for (int i = t; i < 1020; i += 256) {
        int c = i / 340, rr2 = i - c * 340;
        int rr = rr2 / 34, cc = rr2 - rr * 34;
        int y = r0 + rr - 1, xx = cc - 1;
        float v = 0.f;
        if (y >= 0 && y < 32 && xx >= 0 && xx < 32) v = xi[c * 1024 + y * 32 + xx];
        sl[c][rr][cc] = v;
    }
    for (int i = t; i < 1728; i += 256) wl[i] = w[i];
    if (t < 64) bl[t] = bias[t];
    __syncthreads();

    int rr = t >> 5, col = t & 31;
    float iv[27];
    #pragma unroll
    for (int c = 0; c < 3; c++)
        #pragma unroll
        for (int dy = 0; dy < 3; dy++)
            #pragma unroll
            for (int dx = 0; dx < 3; dx++)
                iv[c * 9 + dy * 3 + dx] = sl[c][rr + dy][col + dx];

    __hip_bfloat16 ov[64];
    #pragma unroll 4
    for (int co = 0; co < 64; co++) {
        float s = bl[co];
        const float* wc = &wl[co * 27];
        #pragma unroll
        for (int k = 0; k < 27; k++) s += iv[k] * wc[k];
        ov[co] = __float2bfloat16(fmaxf(s, 0.f));
    }
    char* base = (char*)out + (size_t)img * IMG_B + (r0 + rr + 1) * ROW_B + (col + 1) * 16;
    const uint4* srcv = (const uint4*)ov;
    #pragma unroll
    for (int c8 = 0; c8 < 8; c8++)
        *(uint4*)(base + c8 * C8_B) = srcv[c8];
}

// ---------------- 3x3 SAME conv: implicit GEMM, DMA-staged A, B reg-ring ----------------
// grid = cb*4 (img-major), 256 thr / 4 waves, strip of 8 output rows.
// Staging: strip's 10 padded rows = contiguous 43520 B -> global_load_lds
// width=16 (async DMA, zero VGPR/ds_write cost). A-frag ds_read_b128 are
// bank-balanced by the c8-interleaved layout (no padding needed).
// K-loop: 18 steps (9 taps x 2 ci-halves) x 16 MFMA; B in depth-3 reg ring.
// Epilogue: bias -> bf16 -> LDS bounce -> coalesced 16B skip/ReLU/store.
// MEAN: fuses spatial sum into epilogue (atomicAdd per strip-block).
template<bool ADD, bool MEAN>
__global__ __launch_bounds__(256, 3) void conv3x3_dma(
    const __hip_bfloat16* __restrict__ act, const __hip_bfloat16* __restrict__ wts,
    const float* __restrict__ bias, const __hip_bfloat16* __restrict__ skip,
    __hip_bfloat16* __restrict__ out, int cb, float* __restrict__ msum)
{
    __shared__ char sl[43520];
    __shared__ float pmean[8][8];
    int bid = blockIdx.x;
    int img = bid % cb, strip = bid / cb;
    int t = threadIdx.x;
    int w = t >> 6, lane = t & 63;
    int m = lane & 15, q = lane >> 4;

    // ---- async DMA staging: 2720 granules, contiguous ----
    const char* gsrc = (const char*)act + (size_t)img * IMG_B + (size_t)(strip * 8) * ROW_B;
    #pragma unroll
    for (int k = 0; k < 11; k++) {
        int u = t + 256 * k;
        if (u < 2720) async_g2l(gsrc + u * 16, sl + u * 16);
    }
    __syncthreads();

    // ---- fragment bases: LDS addr = lr*4352 + (kb*4+q)*544 + col*16 ----
    int abase[4];
    #pragma unroll
    for (int mt = 0; mt < 4; mt++)
        abase[mt] = (2 * w + (mt >> 1)) * ROW_B + q * C8_B + ((mt & 1) * 16 + m) * 16;
    const char* wb = (const char*)wts;
    int bbase[4];
    #pragma unroll
    for (int nt = 0; nt < 4; nt++)
        bbase[nt] = (nt * 16 + m) * 128 + q * 16;

    f32x4 acc[4][4] = {};
    bf16x8 a[2][4], b[3][4];

    #define ALOAD(s, buf)                                                      \
        {                                                                      \
            const int tap_ = (s) >> 1, kb_ = (s) & 1;                          \
            const int dy_ = tap_ / 3, dx_ = tap_ - dy_ * 3;                    \
            const int aoff_ = dy_ * ROW_B + kb_ * (4 * C8_B) + dx_ * 16;       \
            _Pragma("unroll")                                                  \
            for (int mt = 0; mt < 4; mt++)                                     \
                a[buf][mt] = *(const bf16x8*)(sl + abase[mt] + aoff_);         \
        }
    #define BLOAD(s, buf)                                                      \
        {                                                                      \
            const int boff_ = ((s) >> 1) * 8192 + ((s) & 1) * 64;              \
            _Pragma("unroll")                                                  \
            for (int nt = 0; nt < 4; nt++)                                     \
                b[buf][nt] = *(const bf16x8*)(wb + bbase[nt] + boff_);         \
        }

    BLOAD(0, 0) BLOAD(1, 1) BLOAD(2, 2)
    ALOAD(0, 0)
    #pragma unroll
    for (int s = 0; s < 18; s++) {
        int cur = s & 1;
        if (s < 17) ALOAD(s + 1, cur ^ 1)
        #pragma unroll
        for (int mt = 0; mt < 4; mt++)
            #pragma unroll
            for (int nt = 0; nt < 4; nt++)
                acc[mt][nt] = __builtin_amdgcn_mfma_f32_16x16x32_bf16(
                    a[cur][mt], b[s % 3][nt], acc[mt][nt], 0, 0, 0);
        if (s + 3 < 18) BLOAD(s + 3, (s + 3) % 3)
    }
    #undef ALOAD
    #undef BLOAD

    // ---- bounce: acc+bias -> bf16 -> LDS [(or*8+c8)*32+col] granules ----
    __syncthreads();   // all K-loop LDS reads done before overwrite
    #pragma unroll
    for (int nt = 0; nt < 4; nt++) {
        float bv = bias[nt * 16 + m];
        #pragma unroll
        for (int mt = 0; mt < 4; mt++) {
            int or_ = 2 * w + (mt >> 1);
            int colb = (mt & 1) * 16 + q * 4;
            int co = nt * 16 + m;
            #pragma unroll
            for (int r = 0; r < 4; r++) {
                __hip_bfloat16 hv = __float2bfloat16(acc[mt][nt][r] + bv);
                *(__hip_bfloat16*)(sl + ((or_ * 8 + (co >> 3)) * 32 + colb + r) * 16
                                      + (co & 7) * 2) = hv;
            }
        }
    }
    __syncthreads();

    // ---- coalesced global phase (+ optional spatial-sum) ----
    char* oimg = (char*)out + (size_t)img * IMG_B;
    const char* simg = (const char*)skip + (size_t)img * IMG_B;
    int col = t & 31, sub = t >> 5;    // sub = c8, fixed per lane
    float s8[8];
    #pragma unroll
    for (int e = 0; e < 8; e++) s8[e] = 0.f;
    #pragma unroll
    for (int pass = 0; pass < 8; pass++) {
        int g = pass * 8 + sub;                       // localrow=pass, c8=sub
        int goff = (strip * 8 + pass + 1) * ROW_B + sub * C8_B + (col + 1) * 16;
        bf16x8 v = *(const bf16x8*)(sl + (g * 32 + col) * 16);
        bf16x8 o;
        if (ADD) {
            bf16x8 sv = *(const bf16x8*)(simg + goff);
            #pragma unroll
            for (int e = 0; e < 8; e++) {
                float f = __bfloat162float(((__hip_bfloat16*)&v)[e])
                        + __bfloat162float(((__hip_bfloat16*)&sv)[e]);
                f = fmaxf(f, 0.f);
                if (MEAN) s8[e] += f;
                ((__hip_bfloat16*)&o)[e] = __float2bfloat16(f);
            }
        } else {
            #pragma unroll
            for (int e = 0; e < 8; e++) {
                float f = fmaxf(__bfloat162float(((__hip_bfloat16*)&v)[e]), 0.f);
                ((__hip_bfloat16*)&o)[e] = __float2bfloat16(f);
            }
        }
        *(bf16x8*)(oimg + goff) = o;
    }

    if (MEAN) {
        #pragma unroll
        for (int off = 1; off <= 16; off <<= 1)
            #pragma unroll
            for (int e = 0; e < 8; e++) s8[e] += __shfl_xor(s8[e], off, 64);
        if ((lane & 31) == 0)
            #pragma unroll
            for (int e = 0; e < 8; e++) pmean[sub][e] = s8[e];
        __syncthreads();
        if (t < 64)
            atomicAdd(&msum[(size_t)img * 64 + t], pmean[t >> 3][t & 7]);
    }
}

// ---------------- final: mean-scale + FC + masked merge ----------------
__global__ __launch_bounds__(256) void res_fc(const float* __restrict__ msum,
    const float* __restrict__ rfc, const float* __restrict__ rfb,
    const int* __restrict__ flags, float* __restrict__ out)
{
    int idx = blockIdx.x * 256 + threadIdx.x;
    if (idx >= BATCH * 10) return;
    int img = idx / 10, d = idx - img * 10;
    if (!flags[img]) return;
    const float* mrow = msum + (size_t)img * 64;
    float s = rfb[d];
    for (int c = 0; c < 64; c++) s += mrow[c] * (1.f / 1024.f) * rfc[c * 10 + d];
    out[idx] = s;
}

extern "C" void kernel_launch(void* const* d_in, const int* in_sizes, int n_in,
                              void* d_out, int out_size, void* d_ws, size_t ws_size,
                              hipStream_t stream)
{
    const float* x    = (const float*)d_in[0];
    const float* thr  = (const float*)d_in[1];
    const int*   labels = (const int*)d_in[2];
    const float* lw1 = (const float*)d_in[3];  const float* lb1 = (const float*)d_in[4];
    const float* lw2 = (const float*)d_in[5];  const float* lb2 = (const float*)d_in[6];
    const float* lfc1 = (const float*)d_in[7]; const float* lfb1 = (const float*)d_in[8];
    const float* lfc2 = (const float*)d_in[9]; const float* lfb2 = (const float*)d_in[10];
    const float* lfc3 = (const float*)d_in[11];const float* lfb3 = (const float*)d_in[12];
    const float* rw0 = (const float*)d_in[13]; const float* rb0 = (const float*)d_in[14];
    const float* rw1a = (const float*)d_in[15];const float* rb1a = (const float*)d_in[16];
    const float* rw1b = (const float*)d_in[17];const float* rb1b = (const float*)d_in[18];
    const float* rw2a = (const float*)d_in[19];const float* rb2a = (const float*)d_in[20];
    const float* rw2b = (const float*)d_in[21];const float* rb2b = (const float*)d_in[22];
    const float* rfc = (const float*)d_in[23]; const float* rfb = (const float*)d_in[24];

    float* out  = (float*)d_out;
    float* conf = out + (size_t)BATCH * 10;

    int nc = 2;
    while (nc < 16 &&
           2ull * (size_t)(BATCH / nc) * (size_t)IMG_B + 294912ull + 4096ull + 262144ull > ws_size)
        nc <<= 1;
    int cb = BATCH / nc;

    __hip_bfloat16* A  = (__hip_bfloat16*)d_ws;
    __hip_bfloat16* Bb = A + (size_t)cb * IMG_ELEMS;
    __hip_bfloat16* wprep = Bb + (size_t)cb * IMG_ELEMS;
    int* flags = (int*)((char*)wprep + 294912);
    float* msum = (float*)(flags + 1024);

    hipMemsetAsync(conf, 0, 100 * sizeof(float), stream);
    hipMemsetAsync(msum, 0, (size_t)BATCH * 64 * sizeof(float), stream);

    prep_weights<<<(4 * 36864 + 255) / 256, 256, 0, stream>>>(rw1a, rw1b, rw2a, rw2b, wprep);

    int zb = (cb * 1056 + 255) / 256;
    zero_borders<<<zb, 256, 0, stream>>>(A, cb);
    zero_borders<<<zb, 256, 0, stream>>>(Bb, cb);

    lenet_full<<<BATCH, 256, 0, stream>>>(x,
        lw1, lb1, lw2, lb2, lfc1, lfb1, lfc2, lfb2, lfc3, lfb3,
        labels, thr, out, conf, flags);

    const __hip_bfloat16* W1a = wprep;
    const __hip_bfloat16* W1b = wprep + 36864;
    const __hip_bfloat16* W2a = wprep + 2 * 36864;
    const __hip_bfloat16* W2b = wprep + 3 * 36864;

    for (int c0 = 0; c0 < BATCH; c0 += cb) {
        const float* xc = x + (size_t)c0 * 3072;
        conv0_nhwc<<<cb * 4, 256, 0, stream>>>(xc, rw0, rb0, A, cb);
        conv3x3_dma<false, false><<<cb * 4, 256, 0, stream>>>(A,  W1a, rb1a, nullptr, Bb, cb, nullptr);
        conv3x3_dma<true,  false><<<cb * 4, 256, 0, stream>>>(Bb, W1b, rb1b, A, A, cb, nullptr);
        conv3x3_dma<false, false><<<cb * 4, 256, 0, stream>>>(A,  W2a, rb2a, nullptr, Bb, cb, nullptr);
        conv3x3_dma<true,  true ><<<cb * 4, 256, 0, stream>>>(Bb, W2b, rb2b, A, A, cb,
                                                              msum + (size_t)c0 * 64);
    }

    res_fc<<<(BATCH * 10 + 255) / 256, 256, 0, stream>>>(msum, rfc, rfb, flags, out);
}

// Round 10
// 1057.443 us; speedup vs baseline: 1.4457x; 1.1144x over previous
//
#include <hip/hip_runtime.h>
#include <hip/hip_bf16.h>
#include <math.h>

#define BATCH 1024

typedef __attribute__((ext_vector_type(8))) short bf16x8;
typedef __attribute__((ext_vector_type(4))) float f32x4;

// Padded NHWC activation geometry: [34 rows][34 cols][64 ci] bf16, 147968 B/img
#define IMG_ELEMS 73984
#define PIX_B 128
#define ROW_B 4352            // 34 * 128
// LDS tile: 10 rows x 34 px, pixel stride 144 B (conflict-free ds_read_b128)
#define LPIX_B 144
#define LROW_B 4896           // 34 * 144

// ---------------- weight prep: 4x OIHW fp32 [64][64][3][3] -> bf16 [tap][co][ci] ----------------
__global__ __launch_bounds__(256) void prep_weights(
    const float* __restrict__ w0, const float* __restrict__ w1,
    const float* __restrict__ w2, const float* __restrict__ w3,
    __hip_bfloat16* __restrict__ dst)
{
    int tid = blockIdx.x * 256 + threadIdx.x;
    if (tid >= 4 * 36864) return;
    int c = tid / 36864, r = tid - c * 36864;
    int tap = r / 4096, r2 = r - tap * 4096;
    int co = r2 >> 6, ci = r2 & 63;
    const float* src = (c == 0) ? w0 : (c == 1) ? w1 : (c == 2) ? w2 : w3;
    float v = src[((size_t)co * 64 + ci) * 9 + tap];
    dst[tid] = __float2bfloat16(v);
}

// ---------------- zero pad borders of [cb][34][34][64] bf16 buffer ----------------
__global__ __launch_bounds__(256) void zero_borders(__hip_bfloat16* __restrict__ buf, int cb)
{
    int tid = blockIdx.x * 256 + threadIdx.x;
    int total = cb * 132 * 8;
    if (tid >= total) return;
    int img = tid / 1056, r = tid - img * 1056;
    int pxi = r >> 3, chunk = r & 7;
    int pix;
    if (pxi < 34)       pix = pxi;
    else if (pxi < 68)  pix = 33 * 34 + (pxi - 34);
    else if (pxi < 100) pix = (pxi - 68 + 1) * 34;
    else                pix = (pxi - 100 + 1) * 34 + 33;
    uint4 z = {0, 0, 0, 0};
    *(uint4*)((char*)buf + (size_t)img * 147968 + pix * PIX_B + chunk * 16) = z;
}

// ---------------- LeNet (conv1+conv2+FC+argmax+conf+flags), 1 block = 1 image ----------------
__global__ __launch_bounds__(256) void lenet_full(
    const float* __restrict__ x,
    const float* __restrict__ lw1, const float* __restrict__ lb1,
    const float* __restrict__ lw2, const float* __restrict__ lb2,
    const float* __restrict__ fw1, const float* __restrict__ fb1,
    const float* __restrict__ fw2, const float* __restrict__ fb2,
    const float* __restrict__ fw3, const float* __restrict__ fb3,
    const int* __restrict__ labels, const float* __restrict__ thr,
    float* __restrict__ out, float* __restrict__ conf, int* __restrict__ flags)
{
    __shared__ float xs[3072];
    __shared__ float wl1[450];
    __shared__ float bl1[6];
    __shared__ float wl2[2400];
    __shared__ float bl2[16];
    __shared__ float p1[1176];
    __shared__ float p2[400];
    __shared__ float ps[256];
    __shared__ float h1[120];
    __shared__ float h2[84];
    __shared__ float lg[10];

    int img = blockIdx.x, t = threadIdx.x;
    const float* xi = x + (size_t)img * 3072;
    for (int i = t; i < 3072; i += 256) xs[i] = xi[i];
    for (int i = t; i < 450; i += 256) wl1[i] = lw1[i];
    if (t < 6) bl1[t] = lb1[t];
    for (int i = t; i < 2400; i += 256) wl2[i] = lw2[i];
    if (t < 16) bl2[t] = lb2[t];
    __syncthreads();

    for (int idx = t; idx < 1176; idx += 256) {
        int o = idx / 196, r = idx - o * 196, py = r / 14, px = r - py * 14;
        int y0 = 2 * py, x0 = 2 * px;
        float s00, s01, s10, s11;
        s00 = s01 = s10 = s11 = bl1[o];
        for (int c = 0; c < 3; c++) {
            float pv[6][6];
            #pragma unroll
            for (int i2 = 0; i2 < 6; i2++)
                #pragma unroll
                for (int j2 = 0; j2 < 6; j2++)
                    pv[i2][j2] = xs[c * 1024 + (y0 + i2) * 32 + x0 + j2];
            const float* wc = &wl1[o * 75 + c * 25];
            #pragma unroll
            for (int ky = 0; ky < 5; ky++)
                #pragma unroll
                for (int kx = 0; kx < 5; kx++) {
                    float wv = wc[ky * 5 + kx];
                    s00 += pv[ky][kx] * wv;
                    s01 += pv[ky][kx + 1] * wv;
                    s10 += pv[ky + 1][kx] * wv;
                    s11 += pv[ky + 1][kx + 1] * wv;
                }
        }
        float mm = fmaxf(fmaxf(s00, s01), fmaxf(s10, s11));
        p1[idx] = fmaxf(mm, 0.f);
    }
    __syncthreads();

    for (int idx = t; idx < 400; idx += 256) {
        int o = idx / 25, r = idx - o * 25, py = r / 5, px = r - py * 5;
        int y0 = 2 * py, x0 = 2 * px;
        float s00, s01, s10, s11;
        s00 = s01 = s10 = s11 = bl2[o];
        for (int c = 0; c < 6; c++) {
            float pv[6][6];
            #pragma unroll
            for (int i2 = 0; i2 < 6; i2++)
                #pragma unroll
                for (int j2 = 0; j2 < 6; j2++)
                    pv[i2][j2] = p1[c * 196 + (y0 + i2) * 14 + x0 + j2];
            const float* wc = &wl2[o * 150 + c * 25];
            #pragma unroll
            for (int ky = 0; ky < 5; ky++)
                #pragma unroll
                for (int kx = 0; kx < 5; kx++) {
                    float wv = wc[ky * 5 + kx];
                    s00 += pv[ky][kx] * wv;
                    s01 += pv[ky][kx + 1] * wv;
                    s10 += pv[ky + 1][kx] * wv;
                    s11 += pv[ky + 1][kx + 1] * wv;
                }
        }
        float mm = fmaxf(fmaxf(s00, s01), fmaxf(s10, s11));
        p2[idx] = fmaxf(mm, 0.f);
    }
    __syncthreads();

    {
        int n = t & 127, half = t >> 7;
        float s = 0.f;
        if (n < 120) {
            int k0 = half * 200;
            for (int k = k0; k < k0 + 200; k++) s += p2[k] * fw1[k * 120 + n];
        }
        ps[t] = s;
    }
    __syncthreads();
    if (t < 120) h1[t] = fmaxf(ps[t] + ps[t + 128] + fb1[t], 0.f);
    __syncthreads();
    {
        int n = t & 127, half = t >> 7;
        float s = 0.f;
        if (n < 84) {
            int k0 = half * 60;
            for (int k = k0; k < k0 + 60; k++) s += h1[k] * fw2[k * 84 + n];
        }
        ps[t] = s;
    }
    __syncthreads();
    if (t < 84) h2[t] = fmaxf(ps[t] + ps[t + 128] + fb2[t], 0.f);
    __syncthreads();
    if (t < 10) {
        float s = fb3[t];
        for (int k = 0; k < 84; k++) s += h2[k] * fw3[k * 10 + t];
        lg[t] = s;
        out[(size_t)img * 10 + t] = s;
    }
    __syncthreads();
    if (t == 0) {
        int pred = 0;
        float mm = lg[0];
        #pragma unroll
        for (int j = 1; j < 10; j++) if (lg[j] > mm) { mm = lg[j]; pred = j; }
        float se = 0.f, m2 = -1e30f;
        #pragma unroll
        for (int j = 0; j < 10; j++) {
            se += expf(lg[j] - mm);
            if (j != pred) m2 = fmaxf(m2, lg[j]);
        }
        float gap = (1.f - expf(m2 - mm)) / se;
        flags[img] = (gap <= thr[0]) ? 1 : 0;
        atomicAdd(&conf[labels[img] * 10 + pred], 1.f);
    }
}

// ---------------- conv0: NCHW fp32 [3][32][32] -> padded NHWC bf16, bias+ReLU ----------------
__global__ __launch_bounds__(256) void conv0_nhwc(const float* __restrict__ x,
    const float* __restrict__ w, const float* __restrict__ bias,
    __hip_bfloat16* __restrict__ out, int cb)
{
    __shared__ float sl[3][10][34];
    __shared__ float wl[1728];
    __shared__ float bl[64];
    int bid = blockIdx.x;
    int img = bid % cb, strip = bid / cb;
    int r0 = strip * 8;
    int t = threadIdx.x;
    const float* xi = x + (size_t)img * 3072;
    for (int i = t; i < 1020; i += 256) {
        int c = i / 340, rr2 = i - c * 340;
        int rr = rr2 / 34, cc = rr2 - rr * 34;
        int y = r0 + rr - 1, xx = cc - 1;
        float v = 0.f;
        if (y >= 0 && y < 32 && xx >= 0 && xx < 32) v = xi[c * 1024 + y * 32 + xx];
        sl[c][rr][cc] = v;
    }
    for (int i = t; i < 1728; i += 256) wl[i] = w[i];
    if (t < 64) bl[t] = bias[t];
    __syncthreads();

    int rr = t >> 5, col = t & 31;
    float iv[27];
    #pragma unroll
    for (int c = 0; c < 3; c++)
        #pragma unroll
        for (int dy = 0; dy < 3; dy++)
            #pragma unroll
            for (int dx = 0; dx < 3; dx++)
                iv[c * 9 + dy * 3 + dx] = sl[c][rr + dy][col + dx];

    __hip_bfloat16 ov[64];
    #pragma unroll 4
    for (int co = 0; co < 64; co++) {
        float s = bl[co];
        const float* wc = &wl[co * 27];
        #pragma unroll
        for (int k = 0; k < 27; k++) s += iv[k] * wc[k];
        ov[co] = __float2bfloat16(fmaxf(s, 0.f));
    }
    int pix = (r0 + rr + 1) * 34 + (col + 1);
    uint4* dst = (uint4*)((char*)out + (size_t)img * 147968 + pix * PIX_B);
    const uint4* srcv = (const uint4*)ov;
    #pragma unroll
    for (int j = 0; j < 8; j++) dst[j] = srcv[j];
}

// ---------------- 3x3 SAME conv: implicit GEMM, A in LDS, B reg-ring (r5 proven) ----------------
// grid = cb*4 (img-major), 256 thr / 4 waves, strip of 8 output rows.
// LDS: 10 rows x 34 px x 64 ci bf16 @144 B px-stride (conflict-free b128).
// K-loop: 18 steps (9 taps x 2 ci-halves) x 16 MFMA; A double-buffered from
// LDS, B in depth-3 register ring (~2.5-step prefetch covers L2 latency).
// Epilogue: bias+bf16 -> LDS [px][co] bounce -> coalesced 16 B skip/ReLU/store.
// MEAN: fuses avgpool spatial sum (atomicAdd per strip-block into msum).
template<bool ADD, bool MEAN>
__global__ __launch_bounds__(256, 3) void conv3x3_lds(
    const __hip_bfloat16* __restrict__ act, const __hip_bfloat16* __restrict__ wts,
    const float* __restrict__ bias, const __hip_bfloat16* __restrict__ skip,
    __hip_bfloat16* __restrict__ out, int cb, float* __restrict__ msum)
{
    __shared__ char sl[10 * LROW_B];   // 48960 B
    __shared__ float pmean[4][64];
    int bid = blockIdx.x;
    int img = bid % cb, strip = bid / cb;
    int t = threadIdx.x;
    int w = t >> 6, lane = t & 63;
    int m = lane & 15, q = lane >> 4;

    // ---- stage 10 padded rows ----
    const char* gsrc = (const char*)act + (size_t)img * 147968 + (size_t)(strip * 8) * ROW_B;
    for (int i = t; i < 340; i += 256) {
        int r = i / 34, c = i - r * 34;
        const uint4* s = (const uint4*)(gsrc + r * ROW_B + c * PIX_B);
        char* d = sl + r * LROW_B + c * LPIX_B;
        #pragma unroll
        for (int j = 0; j < 8; j++) *(uint4*)(d + j * 16) = s[j];
    }
    __syncthreads();

    int abase[4];
    #pragma unroll
    for (int mt = 0; mt < 4; mt++)
        abase[mt] = (2 * w + (mt >> 1)) * LROW_B + ((mt & 1) * 16 + m) * LPIX_B + q * 16;
    const char* wb = (const char*)wts;
    int bbase[4];
    #pragma unroll
    for (int nt = 0; nt < 4; nt++)
        bbase[nt] = (nt * 16 + m) * 128 + q * 16;

    f32x4 acc[4][4] = {};
    bf16x8 a[2][4], b[3][4];

    #define ALOAD(s, buf)                                                      \
        {                                                                      \
            const int tap_ = (s) >> 1, kb_ = (s) & 1;                          \
            const int dy_ = tap_ / 3, dx_ = tap_ - dy_ * 3;                    \
            const int aoff_ = dy_ * LROW_B + dx_ * LPIX_B + kb_ * 64;          \
            _Pragma("unroll")                                                  \
            for (int mt = 0; mt < 4; mt++)                                     \
                a[buf][mt] = *(const bf16x8*)(sl + abase[mt] + aoff_);         \
        }
    #define BLOAD(s, buf)                                                      \
        {                                                                      \
            const int boff_ = ((s) >> 1) * 8192 + ((s) & 1) * 64;              \
            _Pragma("unroll")                                                  \
            for (int nt = 0; nt < 4; nt++)                                     \
                b[buf][nt] = *(const bf16x8*)(wb + bbase[nt] + boff_);         \
        }

    BLOAD(0, 0) BLOAD(1, 1) BLOAD(2, 2)
    ALOAD(0, 0)
    #pragma unroll
    for (int s = 0; s < 18; s++) {
        int cur = s & 1;
        if (s < 17) ALOAD(s + 1, cur ^ 1)
        #pragma unroll
        for (int mt = 0; mt < 4; mt++)
            #pragma unroll
            for (int nt = 0; nt < 4; nt++)
                acc[mt][nt] = __builtin_amdgcn_mfma_f32_16x16x32_bf16(
                    a[cur][mt], b[s % 3][nt], acc[mt][nt], 0, 0, 0);
        if (s + 3 < 18) BLOAD(s + 3, (s + 3) % 3)
    }
    #undef ALOAD
    #undef BLOAD

    // ---- epilogue: acc+bias -> bf16 -> LDS [px][co] bounce ----
    __syncthreads();
    #pragma unroll
    for (int nt = 0; nt < 4; nt++) {
        float bv = bias[nt * 16 + m];
        #pragma unroll
        for (int mt = 0; mt < 4; mt++) {
            int pl = (2 * w + (mt >> 1)) * 32 + (mt & 1) * 16 + q * 4;
            #pragma unroll
            for (int r = 0; r < 4; r++) {
                __hip_bfloat16 hv = __float2bfloat16(acc[mt][nt][r] + bv);
                *(__hip_bfloat16*)(sl + (size_t)(pl + r) * LPIX_B + (nt * 16 + m) * 2) = hv;
            }
        }
    }
    __syncthreads();

    // ---- coalesced global phase (+ optional spatial-sum) ----
    char* oimg = (char*)out + (size_t)img * 147968;
    const char* simg = (const char*)skip + (size_t)img * 147968;
    int j = t & 7, pxl = t >> 3;
    float s8[8];
    #pragma unroll
    for (int e = 0; e < 8; e++) s8[e] = 0.f;
    #pragma unroll
    for (int pass = 0; pass < 8; pass++) {
        int goff = ((strip * 8 + pass + 1) * 34 + (pxl + 1)) * PIX_B + j * 16;
        bf16x8 v = *(const bf16x8*)(sl + (size_t)(pxl + 32 * pass) * LPIX_B + j * 16);
        bf16x8 o;
        if (ADD) {
            bf16x8 sv = *(const bf16x8*)(simg + goff);
            #pragma unroll
            for (int e = 0; e < 8; e++) {
                float f = __bfloat162float(((__hip_bfloat16*)&v)[e])
                        + __bfloat162float(((__hip_bfloat16*)&sv)[e]);
                f = fmaxf(f, 0.f);
                if (MEAN) s8[e] += f;
                ((__hip_bfloat16*)&o)[e] = __float2bfloat16(f);
            }
        } else {
            #pragma unroll
            for (int e = 0; e < 8; e++) {
                float f = fmaxf(__bfloat162float(((__hip_bfloat16*)&v)[e]), 0.f);
                ((__hip_bfloat16*)&o)[e] = __float2bfloat16(f);
            }
        }
        *(bf16x8*)(oimg + goff) = o;
    }
    if (MEAN) {
        // reduce over the 8 px-slots within the wave (lane bits 3,4,5)
        #pragma unroll
        for (int off = 8; off <= 32; off <<= 1)
            #pragma unroll
            for (int e = 0; e < 8; e++) s8[e] += __shfl_xor(s8[e], off, 64);
        if (lane < 8)
            #pragma unroll
            for (int e = 0; e < 8; e++) pmean[w][(lane & 7) * 8 + e] = s8[e];
        __syncthreads();
        if (t < 64)
            atomicAdd(&msum[(size_t)img * 64 + t],
                      pmean[0][t] + pmean[1][t] + pmean[2][t] + pmean[3][t]);
    }
}

// ---------------- final: mean-scale + FC + masked merge ----------------
__global__ __launch_bounds__(256) void res_fc(const float* __restrict__ msum,
    const float* __restrict__ rfc, const float* __restrict__ rfb,
    const int* __restrict__ flags, float* __restrict__ out)
{
    int idx = blockIdx.x * 256 + threadIdx.x;
    if (idx >= BATCH * 10) return;
    int img = idx / 10, d = idx - img * 10;
    if (!flags[img]) return;
    const float* mrow = msum + (size_t)img * 64;
    float s = rfb[d];
    for (int c = 0; c < 64; c++) s += mrow[c] * (1.f / 1024.f) * rfc[c * 10 + d];
    out[idx] = s;
}

extern "C" void kernel_launch(void* const* d_in, const int* in_sizes, int n_in,
                              void* d_out, int out_size, void* d_ws, size_t ws_size,
                              hipStream_t stream)
{
    const float* x    = (const float*)d_in[0];
    const float* thr  = (const float*)d_in[1];
    const int*   labels = (const int*)d_in[2];
    const float* lw1 = (const float*)d_in[3];  const float* lb1 = (const float*)d_in[4];
    const float* lw2 = (const float*)d_in[5];  const float* lb2 = (const float*)d_in[6];
    const float* lfc1 = (const float*)d_in[7]; const float* lfb1 = (const float*)d_in[8];
    const float* lfc2 = (const float*)d_in[9]; const float* lfb2 = (const float*)d_in[10];
    const float* lfc3 = (const float*)d_in[11];const float* lfb3 = (const float*)d_in[12];
    const float* rw0 = (const float*)d_in[13]; const float* rb0 = (const float*)d_in[14];
    const float* rw1a = (const float*)d_in[15];const float* rb1a = (const float*)d_in[16];
    const float* rw1b = (const float*)d_in[17];const float* rb1b = (const float*)d_in[18];
    const float* rw2a = (const float*)d_in[19];const float* rb2a = (const float*)d_in[20];
    const float* rw2b = (const float*)d_in[21];const float* rb2b = (const float*)d_in[22];
    const float* rfc = (const float*)d_in[23]; const float* rfb = (const float*)d_in[24];

    float* out  = (float*)d_out;
    float* conf = out + (size_t)BATCH * 10;

    // nc >= 2: both activation buffers (151 MB) have a chance to stay
    // L3-resident; nc=1 (303 MB) demonstrably thrashes L3.
    int nc = 2;
    while (nc < 16 &&
           2ull * (size_t)(BATCH / nc) * 147968ull + 294912ull + 4096ull + 262144ull > ws_size)
        nc <<= 1;
    int cb = BATCH / nc;

    __hip_bfloat16* A  = (__hip_bfloat16*)d_ws;
    __hip_bfloat16* Bb = A + (size_t)cb * IMG_ELEMS;
    __hip_bfloat16* wprep = Bb + (size_t)cb * IMG_ELEMS;
    int* flags = (int*)((char*)wprep + 294912);
    float* msum = (float*)(flags + 1024);

    hipMemsetAsync(conf, 0, 100 * sizeof(float), stream);
    hipMemsetAsync(msum, 0, (size_t)BATCH * 64 * sizeof(float), stream);

    prep_weights<<<(4 * 36864 + 255) / 256, 256, 0, stream>>>(rw1a, rw1b, rw2a, rw2b, wprep);

    int zb = (cb * 1056 + 255) / 256;
    zero_borders<<<zb, 256, 0, stream>>>(A, cb);
    zero_borders<<<zb, 256, 0, stream>>>(Bb, cb);

    lenet_full<<<BATCH, 256, 0, stream>>>(x,
        lw1, lb1, lw2, lb2, lfc1, lfb1, lfc2, lfb2, lfc3, lfb3,
        labels, thr, out, conf, flags);

    const __hip_bfloat16* W1a = wprep;
    const __hip_bfloat16* W1b = wprep + 36864;
    const __hip_bfloat16* W2a = wprep + 2 * 36864;
    const __hip_bfloat16* W2b = wprep + 3 * 36864;

    for (int c0 = 0; c0 < BATCH; c0 += cb) {
        const float* xc = x + (size_t)c0 * 3072;
        conv0_nhwc<<<cb * 4, 256, 0, stream>>>(xc, rw0, rb0, A, cb);
        conv3x3_lds<false, false><<<cb * 4, 256, 0, stream>>>(A,  W1a, rb1a, nullptr, Bb, cb, nullptr);
        conv3x3_lds<true,  false><<<cb * 4, 256, 0, stream>>>(Bb, W1b, rb1b, A, A, cb, nullptr);
        conv3x3_lds<false, false><<<cb * 4, 256, 0, stream>>>(A,  W2a, rb2a, nullptr, Bb, cb, nullptr);
        conv3x3_lds<true,  true ><<<cb * 4, 256, 0, stream>>>(Bb, W2b, rb2b, A, A, cb,
                                                              msum + (size_t)c0 * 64);
    }

    res_fc<<<(BATCH * 10 + 255) / 256, 256, 0, stream>>>(msum, rfc, rfb, flags, out);
}